// Round 1
// baseline (85.281 us; speedup 1.0000x reference)
//
#include <hip/hip_runtime.h>

// HWnet evaluate: B scalar queries against a sorted uniform grid of T anchors.
// For each query: nearest-anchor argmin (exact, via rounding + float32 neighbor
// check replicating jnp.argmin first-min tie-break), 9-wide window softmax of
// -(x-ev)^2 * takecare[raw_idx], weighted sum of vector_table rows -> [B,64].
//
// Layout: 16 lanes per query, lane owns float4 of D=64. Wave = 4 queries.
// Gathers are 256B contiguous rows (L2-resident 512KB table); output store is
// 1KB/wave coalesced.

constexpr int Bq = 131072;
constexpr int Tt = 2048;
constexpr int Dd = 64;
constexpr int Ee = 4;
constexpr int Ww = 2 * Ee + 1;   // 9

__global__ __launch_bounds__(256) void hwnet_kernel(
    const float* __restrict__ x,
    const float* __restrict__ ev,
    const float* __restrict__ tk,
    const float* __restrict__ vec,
    float* __restrict__ out)
{
    const int tid = blockIdx.x * blockDim.x + threadIdx.x;
    const int q = tid >> 4;       // query index
    const int l = tid & 15;       // float4 slot within D=64
    if (q >= Bq) return;

    const float xv = x[q];

    // Nearest anchor on the uniform grid, then exact float32 neighbor check.
    const float e0 = ev[0];
    const float eN = ev[Tt - 1];
    const float step = (eN - e0) * (1.0f / (float)(Tt - 1));
    int i0 = (int)floorf((xv - e0) / step + 0.5f);
    i0 = min(max(i0, 0), Tt - 1);
    const int lo = max(i0 - 1, 0);
    const int hi = min(i0 + 1, Tt - 1);

    int idx = lo;
    float dlo = xv - ev[lo];
    float dbest = dlo * dlo;
    for (int j = lo + 1; j <= hi; ++j) {
        float d = xv - ev[j];
        d = d * d;
        if (d < dbest) { dbest = d; idx = j; }   // strict <: first-min tie-break
    }

    const float takecare = tk[idx];               // raw (unclamped) index!
    const int idxc = min(max(idx, Ee), Tt - 1 - Ee);
    const int base = idxc - Ee;

    // Window logits + softmax (max-subtracted, as jax.nn.softmax does).
    float w[Ww];
    float m = -3.4e38f;
    #pragma unroll
    for (int j = 0; j < Ww; ++j) {
        const float d = xv - ev[base + j];
        w[j] = -d * d * takecare;
        m = fmaxf(m, w[j]);
    }
    float s = 0.0f;
    #pragma unroll
    for (int j = 0; j < Ww; ++j) {
        w[j] = __expf(w[j] - m);
        s += w[j];
    }
    const float inv = 1.0f / s;

    // Weighted sum of 9 vector rows, float4 per lane.
    float4 acc = make_float4(0.f, 0.f, 0.f, 0.f);
    const float* vbase = vec + (size_t)base * Dd + l * 4;
    #pragma unroll
    for (int j = 0; j < Ww; ++j) {
        const float4 v = *reinterpret_cast<const float4*>(vbase + j * Dd);
        const float wj = w[j] * inv;
        acc.x += wj * v.x;
        acc.y += wj * v.y;
        acc.z += wj * v.z;
        acc.w += wj * v.w;
    }
    *reinterpret_cast<float4*>(out + (size_t)q * Dd + l * 4) = acc;
}

extern "C" void kernel_launch(void* const* d_in, const int* in_sizes, int n_in,
                              void* d_out, int out_size, void* d_ws, size_t ws_size,
                              hipStream_t stream) {
    const float* x   = (const float*)d_in[0];
    const float* ev  = (const float*)d_in[1];
    const float* tk  = (const float*)d_in[2];
    const float* vec = (const float*)d_in[3];
    // d_in[4] = idx_table (arange(-E,E+1)) — constant by construction, folded in.
    float* out = (float*)d_out;

    const int threads = Bq * 16;         // 16 lanes per query
    const int block = 256;
    const int grid = (threads + block - 1) / block;   // 8192 blocks
    hwnet_kernel<<<grid, block, 0, stream>>>(x, ev, tk, vec, out);
}

// Round 2
// 81.813 us; speedup vs baseline: 1.0424x; 1.0424x over previous
//
#include <hip/hip_runtime.h>

// HWnet evaluate, two-phase:
//  Phase 1: thread-per-query scalar path (argmin on uniform grid + exact fp32
//           neighbor check, 9-wide softmax). Normalized weights+base -> LDS.
//  Phase 2: 16 lanes per query, float4 per lane over D=64; 8 queries/group with
//           explicit next-query 9-row prefetch (double-buffered registers) so
//           gather latency overlaps FMA work.
// This cuts VMEM wave-instructions ~2x (kills the 16x-redundant scalar gathers)
// and replaces the per-wave serial memory chain with pipelined ILP.

constexpr int Bq = 131072;
constexpr int Tt = 2048;
constexpr int Dd = 64;
constexpr int Ee = 4;
constexpr int Ww = 2 * Ee + 1;   // 9

constexpr int BLOCK  = 256;
constexpr int QPB    = 128;            // queries per block
constexpr int GROUPS = BLOCK / 16;     // 16 groups of 16 lanes
constexpr int QPG    = QPB / GROUPS;   // 8 queries per group

__global__ __launch_bounds__(BLOCK) void hwnet_kernel(
    const float* __restrict__ x,
    const float* __restrict__ ev,
    const float* __restrict__ tk,
    const float* __restrict__ vec,
    float* __restrict__ out)
{
    __shared__ int   s_base[QPB];
    __shared__ float s_w[QPB][Ww + 1];   // +1 pad: spread banks

    const int tid = threadIdx.x;
    const int bq0 = blockIdx.x * QPB;

    // ---------------- Phase 1: scalar path, one thread per query ------------
    if (tid < QPB) {
        const int q = bq0 + tid;
        const float xv = x[q];

        const float e0 = ev[0];
        const float eN = ev[Tt - 1];
        const float step = (eN - e0) * (1.0f / (float)(Tt - 1));
        int i0 = (int)floorf((xv - e0) / step + 0.5f);
        i0 = min(max(i0, 0), Tt - 1);
        const int lo = max(i0 - 1, 0);
        const int hi = min(i0 + 1, Tt - 1);

        int idx = lo;
        float d0 = xv - ev[lo];
        float dbest = d0 * d0;
        for (int j = lo + 1; j <= hi; ++j) {
            float d = xv - ev[j];
            d = d * d;
            if (d < dbest) { dbest = d; idx = j; }   // strict <: first-min tie-break
        }

        const float takecare = tk[idx];              // raw (unclamped) index!
        const int idxc = min(max(idx, Ee), Tt - 1 - Ee);
        const int base = idxc - Ee;

        float w[Ww];
        float m = -3.4e38f;
        #pragma unroll
        for (int j = 0; j < Ww; ++j) {
            const float d = xv - ev[base + j];
            w[j] = -d * d * takecare;
            m = fmaxf(m, w[j]);
        }
        float s = 0.0f;
        #pragma unroll
        for (int j = 0; j < Ww; ++j) {
            w[j] = __expf(w[j] - m);
            s += w[j];
        }
        const float inv = 1.0f / s;

        s_base[tid] = base;
        #pragma unroll
        for (int j = 0; j < Ww; ++j) s_w[tid][j] = w[j] * inv;
    }
    __syncthreads();

    // ---------------- Phase 2: gather + weighted sum, 16 lanes/query --------
    const int g = tid >> 4;        // group id: 0..15
    const int l = tid & 15;        // float4 slot in D=64
    const int lq0 = g * QPG;       // first local query of this group

    float4 cur[Ww];
    {
        const int base = s_base[lq0];
        const float* vb = vec + (size_t)base * Dd + l * 4;
        #pragma unroll
        for (int j = 0; j < Ww; ++j)
            cur[j] = *reinterpret_cast<const float4*>(vb + j * Dd);
    }

    #pragma unroll
    for (int i = 0; i < QPG; ++i) {
        const int lq = lq0 + i;

        // Prefetch next query's 9 rows while we accumulate this one.
        float4 nxt[Ww];
        if (i + 1 < QPG) {
            const int nbase = s_base[lq + 1];
            const float* nvb = vec + (size_t)nbase * Dd + l * 4;
            #pragma unroll
            for (int j = 0; j < Ww; ++j)
                nxt[j] = *reinterpret_cast<const float4*>(nvb + j * Dd);
        }

        float4 acc = make_float4(0.f, 0.f, 0.f, 0.f);
        #pragma unroll
        for (int j = 0; j < Ww; ++j) {
            const float wj = s_w[lq][j];
            acc.x += wj * cur[j].x;
            acc.y += wj * cur[j].y;
            acc.z += wj * cur[j].z;
            acc.w += wj * cur[j].w;
        }
        *reinterpret_cast<float4*>(out + (size_t)(bq0 + lq) * Dd + l * 4) = acc;

        if (i + 1 < QPG) {
            #pragma unroll
            for (int j = 0; j < Ww; ++j) cur[j] = nxt[j];
        }
    }
}

extern "C" void kernel_launch(void* const* d_in, const int* in_sizes, int n_in,
                              void* d_out, int out_size, void* d_ws, size_t ws_size,
                              hipStream_t stream) {
    const float* x   = (const float*)d_in[0];
    const float* ev  = (const float*)d_in[1];
    const float* tk  = (const float*)d_in[2];
    const float* vec = (const float*)d_in[3];
    float* out = (float*)d_out;

    const int grid = Bq / QPB;   // 1024 blocks
    hwnet_kernel<<<grid, BLOCK, 0, stream>>>(x, ev, tk, vec, out);
}